// Round 4
// baseline (99.744 us; speedup 1.0000x reference)
//
#include <hip/hip_runtime.h>

// MockSparseModel: logits[b,t,v] = boost if (mask[b,t]==1 && v==input_ids[b,t]) else 0
// B=8, S=512, V=32768 -> 4096 rows x 32768 fp32 = 512 MiB output, write-BW bound.
//
// R1-R3 lesson: inner-loop shape (predication, VALU, phase rotation) is
// irrelevant — all land at ~99 us / 5.4 TB/s. The 6.8 TB/s rocclr fill runs at
// ~10.9% occupancy (~3.5 waves/CU): few long sequential streams. Our 4096-block
// launch puts ~32 waves/CU -> ~8k interleaved write streams -> DRAM row-buffer
// thrash. This round: 256 blocks, each owning a CONTIGUOUS 16-row (2 MiB)
// region streamed sequentially — replicate the fill's concurrency shape.
//
// Fixup stays race-free: the exact thread that zero-wrote the target float4
// rewrites the boosted element right after that row's fill (same-thread WAW).

#define VOCAB 32768
#define ROWS  (8 * 512)
#define TPB   256
#define BLOCKS 256
#define ROWS_PER_BLOCK (ROWS / BLOCKS)     // 16 contiguous rows = 2 MiB/block
#define ITERS (VOCAB / (TPB * 4))          // 32 float4-stores per thread per row

__global__ __launch_bounds__(TPB) void mock_sparse_scatter(
    const int* __restrict__ input_ids,
    const int* __restrict__ attention_mask,
    const float* __restrict__ boost_p,
    float* __restrict__ out)
{
    const int tid = threadIdx.x;                    // 0..255
    const int r0  = blockIdx.x * ROWS_PER_BLOCK;    // first row of this block

    const float4 z = make_float4(0.0f, 0.0f, 0.0f, 0.0f);

    for (int rr = 0; rr < ROWS_PER_BLOCK; ++rr) {
        const int row = r0 + rr;
        float* __restrict__ rowp = out + (size_t)row * VOCAB;
        float4* __restrict__ outr = reinterpret_cast<float4*>(rowp);

        // Sequential 128 KiB stream per row: j ascends -> block's 4 waves
        // sweep the row front-to-back in 4 KiB steps.
        #pragma unroll
        for (int j = 0; j < ITERS; ++j) {
            outr[j * TPB + tid] = z;                // coalesced 1 KiB/wave-instr
        }

        // Wave-uniform scalars; at most one lane in the block acts.
        const int  id    = input_ids[row];
        const bool valid = (attention_mask[row] == 1) && (id >= 0) && (id < VOCAB);
        if (valid && ((id >> 2) & (TPB - 1)) == tid) {
            rowp[id] = boost_p[0];                  // same thread wrote it above
        }
    }
}

extern "C" void kernel_launch(void* const* d_in, const int* in_sizes, int n_in,
                              void* d_out, int out_size, void* d_ws, size_t ws_size,
                              hipStream_t stream) {
    const int*   input_ids      = (const int*)d_in[0];
    const int*   attention_mask = (const int*)d_in[1];
    const float* boost          = (const float*)d_in[2];
    float*       out            = (float*)d_out;

    mock_sparse_scatter<<<BLOCKS, TPB, 0, stream>>>(input_ids, attention_mask, boost, out);
}

// Round 5
// 90.425 us; speedup vs baseline: 1.1031x; 1.1031x over previous
//
#include <hip/hip_runtime.h>

// MockSparseModel: logits[b,t,v] = boost if (mask[b,t]==1 && v==input_ids[b,t]) else 0
// B=8, S=512, V=32768 -> 4096 rows x 32768 fp32 = 512 MiB output, write-BW bound.
//
// R1-R4 lesson: four structurally different fill kernels (predicated, pure,
// phase-rotated, sequential 256-block) all land 98-100 us (~5.4 TB/s apparent).
// The rocclr fillBufferAligned hits 6.8-6.9 TB/s on 2 GiB dispatches. Decisive
// test: let THAT kernel do the zero-fill (hipMemsetAsync is graph-capturable),
// then scatter the <=4096 boosted elements with a tiny kernel. If this stays
// ~99 us, the gap was size-dependent fixed overhead and we're at the roofline.

#define VOCAB 32768
#define ROWS  (8 * 512)

__global__ __launch_bounds__(256) void boost_scatter(
    const int* __restrict__ input_ids,
    const int* __restrict__ attention_mask,
    const float* __restrict__ boost_p,
    float* __restrict__ out)
{
    const int row = blockIdx.x * 256 + threadIdx.x;   // one thread per (b,t)
    if (row >= ROWS) return;
    const int id = input_ids[row];
    if (attention_mask[row] == 1 && id >= 0 && id < VOCAB) {
        out[(size_t)row * VOCAB + id] = boost_p[0];
    }
}

extern "C" void kernel_launch(void* const* d_in, const int* in_sizes, int n_in,
                              void* d_out, int out_size, void* d_ws, size_t ws_size,
                              hipStream_t stream) {
    const int*   input_ids      = (const int*)d_in[0];
    const int*   attention_mask = (const int*)d_in[1];
    const float* boost          = (const float*)d_in[2];
    float*       out            = (float*)d_out;

    // Zero the whole 512 MiB output with the runtime's fill kernel (6.8+ TB/s
    // on large dispatches). Async on `stream` -> graph-captures as memset node.
    hipMemsetAsync(out, 0, (size_t)out_size * sizeof(float), stream);

    // Then write the <=4096 boosted elements (stream-ordered after the fill).
    boost_scatter<<<ROWS / 256, 256, 0, stream>>>(input_ids, attention_mask, boost, out);
}